// Round 6
// baseline (277.693 us; speedup 1.0000x reference)
//
#include <hip/hip_runtime.h>
#include <climits>

// StreamingRhythmProjector: B=4096 rows x U=2048 units.
// R6: ONE WAVE PER ROW, 4 independent waves packed per 256-thread block
// (grid B/4). ZERO barriers, ZERO LDS: all reductions are in-register
// 64-lane butterflies. Rationale: every prior structure pinned at
// 2.0-2.4 TB/s because the compiler emits s_waitcnt vmcnt(0) before each
// s_barrier (drains loads AND the 96KB of output stores) and co-dispatched
// blocks run phase-locked -> memory idle ~65% of the time. With no barrier
// there is no drain; ~16-20 waves/CU at independent phases keep HBM fed.
// State sr+sc (64 VGPR) -> pass 2 re-reads nothing.

constexpr int UNITS = 2048;
constexpr int BLOCK = 256;           // 4 waves, each owns one row
constexpr int ELEMS = UNITS / 64;    // 32 elems per lane
constexpr int CHUNKS = ELEMS / 4;    // 8 float4 chunks per lane

typedef float f32x4 __attribute__((ext_vector_type(4)));

static __device__ __forceinline__ float bflySum(float v) {
#pragma unroll
  for (int m = 1; m < 64; m <<= 1) v += __shfl_xor(v, m, 64);
  return v;  // all lanes hold the sum
}
static __device__ __forceinline__ int bflyMin(int v) {
#pragma unroll
  for (int m = 1; m < 64; m <<= 1) v = min(v, __shfl_xor(v, m, 64));
  return v;
}

__global__ __launch_bounds__(BLOCK, 4) void rhythm_kernel(
    const float* __restrict__ dur_anchor,    // [B,U]
    const float* __restrict__ unit_mask,     // [B,U] prefix mask (0/1)
    const float* __restrict__ speech_budget, // [B]
    const float* __restrict__ pause_budget,  // [B]
    const float* __restrict__ dur_logratio,  // [B,U]
    const float* __restrict__ pause_weight,  // [B,U]
    const float* __restrict__ boundary,      // [B,U]
    const float* __restrict__ phase_ptr,     // [B]
    const float* __restrict__ backlog,       // [B]
    const float* __restrict__ clock_delta,   // [B]
    const int*   __restrict__ commit_front,  // [B]
    const int*   __restrict__ open_run,      // [B,U]
    float* __restrict__ out,                 // f32, 3*B*U + 4*B
    int B) {
  const int w = threadIdx.x >> 6;            // wave id in block
  const int ln = threadIdx.x & 63;           // lane
  const int row = blockIdx.x * 4 + w;
  if (row >= B) return;
  const size_t base = (size_t)row * UNITS;

  // per-row scalars (wave-uniform)
  const int prev = commit_front[row];
  const float sb = speech_budget[row];
  const float pb = pause_budget[row];
  const float pp = phase_ptr[row];
  const float bl = backlog[row];
  const float cd = clock_delta[row];

  // ---- pass 1: stream all 6 arrays once; keep sr+sc in registers ----
  float sv_sr[ELEMS];  // masked speech_raw (0 where mask==0, else >= 1)
  float sv_sc[ELEMS];  // masked pause score
  float sum_sr = 0.f, sum_sc = 0.f, sum_m = 0.f;
  int min_open = INT_MAX;

#pragma unroll
  for (int c = 0; c < CHUNKS; ++c) {
    const int e0 = c * 256 + 4 * ln;         // wave covers 1KB contiguous
    const float4 a4 = *(const float4*)(dur_anchor   + base + e0);
    const float4 m4 = *(const float4*)(unit_mask    + base + e0);
    const float4 l4 = *(const float4*)(dur_logratio + base + e0);
    const float4 p4 = *(const float4*)(pause_weight + base + e0);
    const float4 b4 = *(const float4*)(boundary     + base + e0);
    const int4   o4 = *(const int4*)(open_run       + base + e0);
    const float av[4] = {a4.x, a4.y, a4.z, a4.w};
    const float mv[4] = {m4.x, m4.y, m4.z, m4.w};
    const float lv[4] = {l4.x, l4.y, l4.z, l4.w};
    const float pv[4] = {p4.x, p4.y, p4.z, p4.w};
    const float bv[4] = {b4.x, b4.y, b4.z, b4.w};
    const int   ov[4] = {o4.x, o4.y, o4.z, o4.w};
#pragma unroll
    for (int j = 0; j < 4; ++j) {
      const int k = c * 4 + j;
      const float m = mv[j];
      const float a = fmaxf(av[j], 1.0f);                      // MIN_SPEECH_FRAMES
      const float bse = a * __expf(lv[j]);
      const float sr = fmaxf(fminf(bse, 3.0f * a), 1.0f) * m;  // MAX_SPEECH_EXPAND
      const float sc = fmaxf(pv[j], 0.0f) * (0.5f + bv[j]) * m;
      sv_sr[k] = sr;
      sv_sc[k] = sc;
      sum_sr += sr;
      sum_sc += sc;
      sum_m += m;
      // prefix mask => (idx < visible) <=> m == 1
      if (ov[j] > 0 && m > 0.5f) min_open = min(min_open, e0 + j);
    }
  }

  // ---- in-register wave reductions (no LDS, no barrier) ----
  const float ts = bflySum(sum_sr);
  const float tc = bflySum(sum_sc);
  const float tm = bflySum(sum_m);
  const int mo = bflyMin(min_open);

  // ---- commit frontier + scales (uniform on all lanes) ----
  const int visible = (int)(tm + 0.5f);               // exact: integer-valued f32
  const int closed = (mo == INT_MAX) ? visible : mo;
  const int relcap = max(visible - 2, 0);             // TAIL_HOLD_UNITS
  int cand = min(relcap, closed);
  const int bidx = min(max(cand - 1, 0), UNITS - 1);
  const float bval = boundary[base + bidx];           // uniform addr, cache-hot
  if (cand > 0 && cand < visible && bval < 0.45f)     // BOUNDARY_COMMIT_THRESHOLD
    cand = max(prev, cand - 1);
  const int commit = max(prev, cand);

  const float sscale = sb / fmaxf(ts, 1e-6f);
  const bool usefb = !(tc > 0.0f);
  const float pscale = pb / fmaxf(tc, 1e-6f);
  const float fbw = pb / fmaxf(tm, 1.0f);
  // analytic effective total (linearity): Sum eff = sscale*ts + pscale*tc
  const float eff_tot = usefb ? (sscale * ts + fbw * tm) : (sscale * ts + pscale * tc);

  // ---- tiny src range-sum over [prev,commit): L1/L2-warm re-read ----
  float src_rng = 0.f;
  for (int i = prev + ln; i < commit; i += 64) src_rng += dur_anchor[base + i];

  // ---- pass 2: outputs from registers + eff range sum ----
  float* __restrict__ out_speech = out;
  float* __restrict__ out_pause  = out + (size_t)B * UNITS;
  float* __restrict__ out_eff    = out + 2 * (size_t)B * UNITS;

  float eff_rng = 0.f;
#pragma unroll
  for (int c = 0; c < CHUNKS; ++c) {
    const int e0 = c * 256 + 4 * ln;
    f32x4 s4, q4, e4;
#pragma unroll
    for (int j = 0; j < 4; ++j) {
      const int k = c * 4 + j;
      const int idx = e0 + j;
      const float sr = sv_sr[k];
      const float m = (sr != 0.0f) ? 1.0f : 0.0f;     // exact: sr>=1 iff mask==1
      const float speech = sr * sscale;
      const float pause = usefb ? (m * fbw) : (sv_sc[k] * pscale);
      const float eff = (speech + pause) * m;
      s4[j] = speech;
      q4[j] = pause;
      e4[j] = eff;
      const bool inr = (idx >= prev) && (idx < commit);
      eff_rng += inr ? eff : 0.f;
    }
    __builtin_nontemporal_store(s4, (f32x4*)(out_speech + base + e0));
    __builtin_nontemporal_store(q4, (f32x4*)(out_pause + base + e0));
    __builtin_nontemporal_store(e4, (f32x4*)(out_eff + base + e0));
  }

  // ---- reduction 2 in-register; lane 0 writes the 4 per-row scalars ----
  const float execp = bflySum(eff_rng);
  const float srcp = bflySum(src_rng);

  if (ln == 0) {
    const bool adv = commit > prev;
    const float nclock = adv ? (cd + (execp - srcp)) : cd;
    const float nback = adv ? fmaxf(nclock, 0.0f) : bl;
    const float vt = fmaxf(eff_tot, 1.0f);
    const float nphase =
        adv ? fminf(fmaxf(pp + execp / vt, 0.0f), 1.0f) : pp;
    const size_t o = 3 * (size_t)B * UNITS;
    out[o + row] = (float)commit;
    out[o + (size_t)B + row] = nphase;
    out[o + 2 * (size_t)B + row] = nback;
    out[o + 3 * (size_t)B + row] = nclock;
  }
}

extern "C" void kernel_launch(void* const* d_in, const int* in_sizes, int n_in,
                              void* d_out, int out_size, void* d_ws, size_t ws_size,
                              hipStream_t stream) {
  const int B = in_sizes[7];  // phase_ptr length
  rhythm_kernel<<<dim3((B + 3) / 4), dim3(BLOCK), 0, stream>>>(
      (const float*)d_in[0],   // dur_anchor_src
      (const float*)d_in[1],   // unit_mask
      (const float*)d_in[2],   // speech_budget_win
      (const float*)d_in[3],   // pause_budget_win
      (const float*)d_in[4],   // dur_logratio_unit
      (const float*)d_in[5],   // pause_weight_unit
      (const float*)d_in[6],   // boundary_latent
      (const float*)d_in[7],   // phase_ptr
      (const float*)d_in[8],   // backlog
      (const float*)d_in[9],   // clock_delta
      (const int*)d_in[10],    // commit_frontier
      (const int*)d_in[11],    // open_run_mask
      (float*)d_out, B);
}

// Round 7
// 244.829 us; speedup vs baseline: 1.1342x; 1.1342x over previous
//
#include <hip/hip_runtime.h>
#include <climits>

// StreamingRhythmProjector: B=4096 rows x U=2048 units, one 256-thread block
// (4 waves) per row — the best-measured skeleton (R2/R4).
// R7: BYTE CUT. Empirical law across R2-R6: dur ~= 23us + hbm_bytes/2.9TB/s
// regardless of structure -> reduce bytes:
//  (1) unit_mask is a PREFIX mask: 2-round wave probe (~2.3KB/row) replaces
//      the 32MB mask stream; m derived as (idx < visible).
//  (2) open_run: chunked early-exit scan (first open ~idx 10 at 10% density)
//      replaces the 32MB stream.
//  (3) loads of the 4 remaining arrays predicated on e0 < visible
//      (E[visible]=1024.5 -> ~half the elements are masked-out tail).
// Logical reads 201 -> ~70MB; writes unchanged.

constexpr int UNITS = 2048;
constexpr int BLOCK = 256;

typedef float f32x4 __attribute__((ext_vector_type(4)));

static __device__ __forceinline__ float waveSum(float v) {
#pragma unroll
  for (int m = 1; m < 64; m <<= 1) v += __shfl_xor(v, m, 64);
  return v;  // all lanes hold the sum
}

__global__ __launch_bounds__(BLOCK, 4) void rhythm_kernel(
    const float* __restrict__ dur_anchor,    // [B,U]
    const float* __restrict__ unit_mask,     // [B,U] prefix mask (0/1)
    const float* __restrict__ speech_budget, // [B]
    const float* __restrict__ pause_budget,  // [B]
    const float* __restrict__ dur_logratio,  // [B,U]
    const float* __restrict__ pause_weight,  // [B,U]
    const float* __restrict__ boundary,      // [B,U]
    const float* __restrict__ phase_ptr,     // [B]
    const float* __restrict__ backlog,       // [B]
    const float* __restrict__ clock_delta,   // [B]
    const int*   __restrict__ commit_front,  // [B]
    const int*   __restrict__ open_run,      // [B,U]
    float* __restrict__ out,                 // f32, 3*B*U + 4*B
    int B) {
  const int row = blockIdx.x;
  const int t = threadIdx.x;
  const int wv = t >> 6, ln = t & 63;
  const size_t base = (size_t)row * UNITS;

  // per-row scalars (wave-uniform)
  const int prev = commit_front[row];
  const float sb = speech_budget[row];
  const float pb = pause_budget[row];
  const float pp = phase_ptr[row];
  const float bl = backlog[row];
  const float cd = clock_delta[row];

  // ---- probe `visible` from the prefix mask (~2.3KB instead of 8KB/row) ----
  // mask[j] = 1 iff j < visible. Round 1: lanes 0..31 tap j=64i+63;
  // hit <=> visible >= 64(i+1); hits form a prefix -> c1 = floor(visible/64).
  // Round 2: 64 contiguous taps at s=64*c1 give the remainder.
  int visible;
  {
    const int i = (ln < 32) ? ln : 0;
    const float v1 = unit_mask[base + 64 * i + 63];
    const int c1 = __popcll(__ballot((ln < 32) && (v1 > 0.5f)));
    if (c1 == 32) {
      visible = 2048;
    } else {
      const int s = 64 * c1;                       // s <= 1984, s+63 <= 2047
      const float v2 = unit_mask[base + s + ln];
      visible = s + __popcll(__ballot(v2 > 0.5f));
    }
  }

  // ---- early-exit scan for first open index in [0, visible) ----
  int min_open = INT_MAX;
  for (int cs = 0; cs < visible; cs += 256) {
    const int e = cs + 4 * ln;                     // e+3 <= 2047 always
    int4 o4 = make_int4(0, 0, 0, 0);
    if (e < visible) o4 = *(const int4*)(open_run + base + e);
    int lm = INT_MAX;
    if (o4.w > 0 && e + 3 < visible) lm = e + 3;
    if (o4.z > 0 && e + 2 < visible) lm = e + 2;
    if (o4.y > 0 && e + 1 < visible) lm = e + 1;
    if (o4.x > 0 && e < visible) lm = e;
    const unsigned long long bb = __ballot(lm != INT_MAX);
    if (bb) {  // lanes ascend in idx; first set lane holds the chunk min
      const int l0 = (int)__ffsll(bb) - 1;
      min_open = __shfl(lm, l0, 64);
      break;
    }
  }

  // ---- pass 1: stream 4 arrays over [0, visible) only ----
  float sv_sr[8];  // masked speech_raw
  float sv_sc[8];  // masked pause score
  float sv_a[2][4] = {};  // not kept — placeholder removed below
  (void)sv_a;
  float sum_sr = 0.f, sum_sc = 0.f;

#pragma unroll
  for (int c = 0; c < 2; ++c) {
    const int e0 = c * 1024 + 4 * t;
    if (e0 < visible) {
      const float4 a4 = *(const float4*)(dur_anchor   + base + e0);
      const float4 l4 = *(const float4*)(dur_logratio + base + e0);
      const float4 p4 = *(const float4*)(pause_weight + base + e0);
      const float4 b4 = *(const float4*)(boundary     + base + e0);
      const float av[4] = {a4.x, a4.y, a4.z, a4.w};
      const float lv[4] = {l4.x, l4.y, l4.z, l4.w};
      const float pv[4] = {p4.x, p4.y, p4.z, p4.w};
      const float bv[4] = {b4.x, b4.y, b4.z, b4.w};
#pragma unroll
      for (int j = 0; j < 4; ++j) {
        const int k = c * 4 + j;
        const float m = (e0 + j < visible) ? 1.0f : 0.0f;
        const float a = fmaxf(av[j], 1.0f);                      // MIN_SPEECH_FRAMES
        const float bse = a * __expf(lv[j]);
        const float sr = fmaxf(fminf(bse, 3.0f * a), 1.0f) * m;  // MAX_SPEECH_EXPAND
        const float sc = fmaxf(pv[j], 0.0f) * (0.5f + bv[j]) * m;
        sv_sr[k] = sr;
        sv_sc[k] = sc;
        sum_sr += sr;
        sum_sc += sc;
      }
    } else {
#pragma unroll
      for (int j = 0; j < 4; ++j) { sv_sr[c * 4 + j] = 0.f; sv_sc[c * 4 + j] = 0.f; }
    }
  }

  // ---- reduction 1: wave butterfly + LDS cross-wave ----
  __shared__ float sf[2][4];
  __shared__ float sg[2][4];
  const float r0 = waveSum(sum_sr);
  const float r1 = waveSum(sum_sc);
  if (ln == 0) { sf[0][wv] = r0; sf[1][wv] = r1; }
  __syncthreads();

  const float ts = sf[0][0] + sf[0][1] + sf[0][2] + sf[0][3];
  const float tc = sf[1][0] + sf[1][1] + sf[1][2] + sf[1][3];
  const float tm = (float)visible;  // sum of prefix mask == visible, exact

  // ---- commit frontier + scales (uniform on all lanes) ----
  const int closed = (min_open == INT_MAX) ? visible : min_open;
  const int relcap = max(visible - 2, 0);             // TAIL_HOLD_UNITS
  int cand = min(relcap, closed);
  const int bidx = min(max(cand - 1, 0), UNITS - 1);
  const float bval = boundary[base + bidx];           // uniform addr, cache-hot
  if (cand > 0 && cand < visible && bval < 0.45f)     // BOUNDARY_COMMIT_THRESHOLD
    cand = max(prev, cand - 1);
  const int commit = max(prev, cand);

  const float sscale = sb / fmaxf(ts, 1e-6f);
  const bool usefb = !(tc > 0.0f);
  const float pscale = pb / fmaxf(tc, 1e-6f);
  const float fbw = pb / fmaxf(tm, 1.0f);
  // analytic effective total (linearity): Sum eff = sscale*ts + pscale*tc
  const float eff_tot = usefb ? (sscale * ts + fbw * tm) : (sscale * ts + pscale * tc);

  // ---- tiny src range-sum over [prev,commit) (cache-warm re-read) ----
  float src_rng = 0.f;
  for (int i = prev + t; i < commit; i += BLOCK) src_rng += dur_anchor[base + i];

  // ---- pass 2: outputs from registers + eff range sum ----
  float* __restrict__ out_speech = out;
  float* __restrict__ out_pause  = out + (size_t)B * UNITS;
  float* __restrict__ out_eff    = out + 2 * (size_t)B * UNITS;

  float eff_rng = 0.f;
#pragma unroll
  for (int c = 0; c < 2; ++c) {
    const int e0 = c * 1024 + 4 * t;
    f32x4 s4, q4, e4;
#pragma unroll
    for (int j = 0; j < 4; ++j) {
      const int k = c * 4 + j;
      const int idx = e0 + j;
      const float m = (idx < visible) ? 1.0f : 0.0f;
      const float speech = sv_sr[k] * sscale;          // sr already masked
      const float pause = usefb ? (m * fbw) : (sv_sc[k] * pscale);
      const float eff = (speech + pause) * m;
      s4[j] = speech;
      q4[j] = pause;
      e4[j] = eff;
      const bool inr = (idx >= prev) && (idx < commit);
      eff_rng += inr ? eff : 0.f;
    }
    __builtin_nontemporal_store(s4, (f32x4*)(out_speech + base + e0));
    __builtin_nontemporal_store(q4, (f32x4*)(out_pause + base + e0));
    __builtin_nontemporal_store(e4, (f32x4*)(out_eff + base + e0));
  }

  // ---- reduction 2: eff_rng, src_rng ----
  const float q0 = waveSum(eff_rng);
  const float q1 = waveSum(src_rng);
  if (ln == 0) { sg[0][wv] = q0; sg[1][wv] = q1; }
  __syncthreads();

  if (t == 0) {
    const float execp = sg[0][0] + sg[0][1] + sg[0][2] + sg[0][3];
    const float srcp  = sg[1][0] + sg[1][1] + sg[1][2] + sg[1][3];
    const bool adv = commit > prev;
    const float nclock = adv ? (cd + (execp - srcp)) : cd;
    const float nback = adv ? fmaxf(nclock, 0.0f) : bl;
    const float vt = fmaxf(eff_tot, 1.0f);
    const float nphase =
        adv ? fminf(fmaxf(pp + execp / vt, 0.0f), 1.0f) : pp;
    const size_t o = 3 * (size_t)B * UNITS;
    out[o + row] = (float)commit;
    out[o + (size_t)B + row] = nphase;
    out[o + 2 * (size_t)B + row] = nback;
    out[o + 3 * (size_t)B + row] = nclock;
  }
}

extern "C" void kernel_launch(void* const* d_in, const int* in_sizes, int n_in,
                              void* d_out, int out_size, void* d_ws, size_t ws_size,
                              hipStream_t stream) {
  const int B = in_sizes[7];  // phase_ptr length
  rhythm_kernel<<<dim3(B), dim3(BLOCK), 0, stream>>>(
      (const float*)d_in[0],   // dur_anchor_src
      (const float*)d_in[1],   // unit_mask
      (const float*)d_in[2],   // speech_budget_win
      (const float*)d_in[3],   // pause_budget_win
      (const float*)d_in[4],   // dur_logratio_unit
      (const float*)d_in[5],   // pause_weight_unit
      (const float*)d_in[6],   // boundary_latent
      (const float*)d_in[7],   // phase_ptr
      (const float*)d_in[8],   // backlog
      (const float*)d_in[9],   // clock_delta
      (const int*)d_in[10],    // commit_frontier
      (const int*)d_in[11],    // open_run_mask
      (float*)d_out, B);
}